// Round 10
// baseline (817.337 us; speedup 1.0000x reference)
//
#include <hip/hip_runtime.h>
#include <hip/hip_fp16.h>
#include <math.h>

#define CC 32
#define CHUNK 4096   // 256 threads * 16 elems, for the rptr scan
#define NCPY 16      // atomic privatization copies
#define REDB 1024    // block size for reduce/permfill (must match between them)

static inline int cdiv(long long a, int b) { return (int)((a + b - 1) / b); }

// ---------- packed privatized degree count ----------
// priv[c][n] packs (out-degree << 16) | in-degree for copy c = blockIdx & 15
__global__ void k_cnt(const int* __restrict__ src, const int* __restrict__ dst,
                      int* __restrict__ priv, int E, int N) {
  int e = blockIdx.x * blockDim.x + threadIdx.x;
  if (e >= E) return;
  int* p = priv + (size_t)(blockIdx.x & (NCPY - 1)) * N;
  atomicAdd(&p[src[e]], 1 << 16);
  atomicAdd(&p[dst[e]], 1);
}

// per node: sum copies -> deg (->dis), cnt; rewrite priv to per-copy exclusive
// cursor bases; per-block degree histogram -> histmat[block][64] (plain store)
__global__ void k_reduce(int* __restrict__ priv, float* __restrict__ dis,
                         int* __restrict__ cnt, int* __restrict__ histmat, int N) {
  __shared__ int lh[64];
  if (threadIdx.x < 64) lh[threadIdx.x] = 0;
  __syncthreads();
  int n = blockIdx.x * REDB + threadIdx.x;
  if (n < N) {
    int vals[NCPY];
    int tot = 0;
#pragma unroll
    for (int c = 0; c < NCPY; ++c) {
      vals[c] = priv[(size_t)c * N + n];
      tot += vals[c];
    }
    int deg = tot >> 16, cv = tot & 0xFFFF;
    dis[n] = (deg > 0) ? rsqrtf((float)deg) : 0.f;
    cnt[n] = cv;
    int acc = 0;
#pragma unroll
    for (int c = 0; c < NCPY; ++c) {
      priv[(size_t)c * N + n] = acc;
      acc += vals[c] & 0xFFFF;
    }
    atomicAdd(&lh[min(cv, 63)], 1);
  }
  __syncthreads();
  if (threadIdx.x < 64) histmat[blockIdx.x * 64 + threadIdx.x] = lh[threadIdx.x];
}

// column scan: histmat[b][bin] -> absolute base of (block b, bin) in perm
__global__ void k_scanhist2(int* __restrict__ histmat, int nb) {
  int lane = threadIdx.x;  // 0..63
  int tot = 0;
  for (int i = 0; i < nb; ++i) tot += histmat[i * 64 + lane];
  __shared__ int sh[64], pf[64];
  sh[lane] = tot;
  __syncthreads();
  if (lane == 0) {
    int acc = 0;
    for (int b = 0; b < 64; ++b) { pf[b] = acc; acc += sh[b]; }
  }
  __syncthreads();
  int acc = pf[lane];
  for (int i = 0; i < nb; ++i) {
    int v = histmat[i * 64 + lane];
    histmat[i * 64 + lane] = acc;
    acc += v;
  }
}

// no global atomics: LDS rank + precomputed per-(block,bin) base
__global__ void k_permfill2(const int* __restrict__ cnt, const int* __restrict__ histmat,
                            int* __restrict__ perm, int N) {
  __shared__ int lh[64], lbase[64];
  if (threadIdx.x < 64) lh[threadIdx.x] = 0;
  __syncthreads();
  int i = blockIdx.x * REDB + threadIdx.x;
  int bin = 0, rank = 0;
  bool act = (i < N);
  if (act) {
    bin = min(cnt[i], 63);
    rank = atomicAdd(&lh[bin], 1);
  }
  __syncthreads();
  if (threadIdx.x < 64) lbase[threadIdx.x] = histmat[blockIdx.x * 64 + threadIdx.x];
  __syncthreads();
  if (act) perm[lbase[bin] + rank] = i;
}

// ---------- CSR rptr: chunk sums -> serial chunk scan -> per-chunk fill ----------
__global__ void k_chunksum(const int* __restrict__ cnt, int* __restrict__ csum, int N) {
  int base = blockIdx.x * CHUNK;
  int v = 0;
  for (int i = threadIdx.x; i < CHUNK; i += 256) {
    int idx = base + i;
    if (idx < N) v += cnt[idx];
  }
  for (int m = 32; m; m >>= 1) v += __shfl_xor(v, m);
  __shared__ int ws[4];
  if ((threadIdx.x & 63) == 0) ws[threadIdx.x >> 6] = v;
  __syncthreads();
  if (threadIdx.x == 0) csum[blockIdx.x] = ws[0] + ws[1] + ws[2] + ws[3];
}

__global__ void k_scancsum(int* __restrict__ csum, int nb, int* __restrict__ rptr,
                           int N, int tot) {
  int acc = 0;
  for (int i = 0; i < nb; ++i) { int v = csum[i]; csum[i] = acc; acc += v; }
  rptr[N] = tot;
}

__global__ void k_fillrptr(int* __restrict__ cnt, const int* __restrict__ csum,
                           int* __restrict__ rptr, int N) {
  int base = blockIdx.x * CHUNK + threadIdx.x * 16;
  int v[16];
  int tot = 0;
#pragma unroll
  for (int q = 0; q < 16; ++q) {
    int idx = base + q;
    v[q] = (idx < N) ? cnt[idx] : 0;
    tot += v[q];
  }
  __shared__ int sh[256];
  sh[threadIdx.x] = tot;
  __syncthreads();
  for (int off = 1; off < 256; off <<= 1) {
    int add = (threadIdx.x >= off) ? sh[threadIdx.x - off] : 0;
    __syncthreads();
    sh[threadIdx.x] += add;
    __syncthreads();
  }
  int excl = sh[threadIdx.x] - tot + csum[blockIdx.x];
#pragma unroll
  for (int q = 0; q < 16; ++q) {
    int idx = base + q;
    if (idx < N) rptr[idx] = excl;
    excl += v[q];
  }
}

// fill interleaved edge records eg[slot] = {src, bits(-dis*dis)}; cursor atomics
// privatized through priv (same copy mapping as k_cnt: blockIdx & 15, B=256)
__global__ void k_fill3(const int* __restrict__ src, const int* __restrict__ dst,
                        const float* __restrict__ dis, const int* __restrict__ rptr,
                        int* __restrict__ priv, int2* __restrict__ eg, int E, int N) {
  int e = blockIdx.x * blockDim.x + threadIdx.x;
  if (e >= E) return;
  int s = src[e], d = dst[e];
  int* pc = priv + (size_t)(blockIdx.x & (NCPY - 1)) * N;
  int p = rptr[d] + atomicAdd(&pc[d], 1);
  int2 v;
  v.x = s;
  v.y = __float_as_int(-dis[s] * dis[d]);
  eg[p] = v;
}

// ---------- fused Cheb step: float4 gather-prop + recurrence + out += Tx@W ----
// 16 lanes per node = 2x8-lane subgroups on interleaved 8-edge batches;
// combine via xor8; GEMM split across subgroups. LPT perm (heaviest first).
__global__ void k_cheb4(const float4* __restrict__ x_in4,
                        const float4* __restrict__ x_sub4,
                        const int* __restrict__ rptr, const int2* __restrict__ eg,
                        const float* __restrict__ W, const int* __restrict__ perm,
                        float scale, float4* __restrict__ tx_out4,
                        float4* __restrict__ out4, int N) {
  __shared__ float wl[1024];
  for (int i = threadIdx.x; i < 1024; i += 256) wl[i] = W[i];
  __syncthreads();
  int gid = blockIdx.x * 16 + (threadIdx.x >> 4);
  int lane16 = threadIdx.x & 15;
  int sub = lane16 >> 3, lane = lane16 & 7;
  if (gid >= N) return;
  int node = perm[N - 1 - gid];
  int beg = rptr[node], end = rptr[node + 1];
  float tx = 0.f, ty = 0.f, tz = 0.f, tw = 0.f;
  for (int base = beg + sub * 8; base < end; base += 16) {
    int rem = end - base;
    int sj = 0; float wjv = 0.f;
    if (lane < rem) {
      int2 v = eg[base + lane];
      sj = v.x;
      wjv = __int_as_float(v.y);
    }
    if (rem >= 8) {
#pragma unroll
      for (int q = 0; q < 8; ++q) {
        int s = __shfl(sj, q, 8);
        float w = __shfl(wjv, q, 8);
        float4 j4 = x_in4[(long long)s * 8 + lane];
        tx += w * j4.x; ty += w * j4.y; tz += w * j4.z; tw += w * j4.w;
      }
    } else {
      for (int q = 0; q < rem; ++q) {
        int s = __shfl(sj, q, 8);
        float w = __shfl(wjv, q, 8);
        float4 j4 = x_in4[(long long)s * 8 + lane];
        tx += w * j4.x; ty += w * j4.y; tz += w * j4.z; tw += w * j4.w;
      }
    }
  }
  // combine the two subgroups (both halves then hold the full sums)
  tx += __shfl_xor(tx, 8, 16);
  ty += __shfl_xor(ty, 8, 16);
  tz += __shfl_xor(tz, 8, 16);
  tw += __shfl_xor(tw, 8, 16);
  long long o = (long long)node * 8 + lane;
  float ta[4] = {scale * tx, scale * ty, scale * tz, scale * tw};
  if (x_sub4) {
    float4 s4 = x_sub4[o];
    ta[0] -= s4.x; ta[1] -= s4.y; ta[2] -= s4.z; ta[3] -= s4.w;
  }
  if (tx_out4 && sub == 0) {
    float4 t4 = {ta[0], ta[1], ta[2], ta[3]};
    tx_out4[o] = t4;
  }
  // GEMM: subgroup s handles c in [s*16, s*16+16), combine via xor8
  float ax = 0.f, ay = 0.f, az = 0.f, aw = 0.f;
  int cbase = sub * 16;
#pragma unroll
  for (int cc = 0; cc < 16; ++cc) {
    int c = cbase + cc;
    float bc = __shfl(ta[c & 3], c >> 2, 8);
    const float4 w4 = *(const float4*)&wl[c * 32 + lane * 4];
    ax += bc * w4.x; ay += bc * w4.y; az += bc * w4.z; aw += bc * w4.w;
  }
  ax += __shfl_xor(ax, 8, 16);
  ay += __shfl_xor(ay, 8, 16);
  az += __shfl_xor(az, 8, 16);
  aw += __shfl_xor(aw, 8, 16);
  if (sub == 0) {
    float4 a4 = out4[o];
    a4.x += ax; a4.y += ay; a4.z += az; a4.w += aw;
    out4[o] = a4;
  }
}

// out[row][col] = T[row][:] @ W[32][32] + bias[col]   (k=0 term, init)
__global__ void k_gemm32b(const float* __restrict__ T, const float* __restrict__ W,
                          const float* __restrict__ bias, float* __restrict__ out,
                          int N) {
  __shared__ float w[1024];
  for (int i = threadIdx.x; i < 1024; i += 256) w[i] = W[i];
  __syncthreads();
  int row = blockIdx.x * 8 + (threadIdx.x >> 5);
  int col = threadIdx.x & 31;
  if (row >= N) return;
  const float* tr = T + (long long)row * 32;
  float acc = 0.f;
#pragma unroll
  for (int c = 0; c < 32; ++c) acc += tr[c] * w[c * 32 + col];
  out[(long long)row * 32 + col] = acc + bias[col];
}

// h = x @ lin_w stored head-packed HALF: lane l in [0,16) of a row holds
// halves {h0[l], h0[l+16], h1[l], h1[l+16]} (8B/lane, 128B/row). Also
// bl = h.att_l, br = h.att_r (f32, float2 over heads). One wave per row.
__global__ void k_gemmh(const float* __restrict__ T, const float* __restrict__ W,
                        const float* __restrict__ attl, const float* __restrict__ attr,
                        __half* __restrict__ h, float* __restrict__ bl,
                        float* __restrict__ br, int N) {
  __shared__ float w[2048];
  for (int i = threadIdx.x; i < 2048; i += 256) w[i] = W[i];
  __syncthreads();
  int row = blockIdx.x * 4 + (threadIdx.x >> 6);
  int col = threadIdx.x & 63;
  if (row >= N) return;
  const float* tr = T + (long long)row * 32;
  float acc = 0.f;
#pragma unroll
  for (int c = 0; c < 32; ++c) acc += tr[c] * w[c * 64 + col];
  int ch = col & 31, hd = col >> 5;
  h[(long long)row * 64 + (ch & 15) * 4 + (ch >> 4) + 2 * hd] = __float2half(acc);
  float pl = acc * attl[col], pr = acc * attr[col];
#pragma unroll
  for (int m = 16; m; m >>= 1) {
    pl += __shfl_xor(pl, m, 64);
    pr += __shfl_xor(pr, m, 64);
  }
  if ((col & 31) == 0) {
    bl[row * 2 + (col >> 5)] = pl;
    br[row * 2 + (col >> 5)] = pr;
  }
}

// ---------- fused SuperGAT: 32 lanes per node = 2x16-lane subgroups on
// interleaved 16-edge batches; fp16 head-packed h; head-split butterfly;
// no-max softmax; self-loop on sub 0; final xor16 combine; LPT perm.
__device__ inline float4 h4f(int2 r) {
  __half2 lo = *reinterpret_cast<__half2*>(&r.x);
  __half2 hi = *reinterpret_cast<__half2*>(&r.y);
  float2 a = __half22float2(lo), b = __half22float2(hi);
  return make_float4(a.x, a.y, b.x, b.y);
}

__device__ inline void gat_edge(const float4& j4, const float4& i4, bool hiH,
                                float bxq, float byq, float brh,
                                float& s0, float& s1, float4& v) {
  float d0 = j4.x * i4.x + j4.y * i4.y;
  float d1 = j4.z * i4.z + j4.w * i4.w;
  d0 += __shfl_xor(d0, 8, 16);
  d1 += __shfl_xor(d1, 8, 16);
  float dc = hiH ? d1 : d0;
  dc += __shfl_xor(dc, 4, 16);
  dc += __shfl_xor(dc, 2, 16);
  dc += __shfl_xor(dc, 1, 16);
  float lin = (hiH ? byq : bxq) + brh;
  float a = lin / (1.f + __expf(-dc));
  a = (a > 0.f) ? a : 0.2f * a;
  float ec = __expf(a);
  float e0 = __shfl(ec, 0, 16), e1 = __shfl(ec, 8, 16);
  s0 += e0; s1 += e1;
  v.x += e0 * j4.x; v.y += e0 * j4.y; v.z += e1 * j4.z; v.w += e1 * j4.w;
}

__global__ void k_expgat4(const int2* __restrict__ h2, const int* __restrict__ rptr,
                          const int2* __restrict__ eg, const float2* __restrict__ bl,
                          const float2* __restrict__ br, const float* __restrict__ gb,
                          const int* __restrict__ perm, float* __restrict__ y,
                          float* __restrict__ bns, int N) {
  __shared__ float ls[64];
  for (int i = threadIdx.x; i < 64; i += 256) ls[i] = 0.f;
  __syncthreads();
  int gid = blockIdx.x * 8 + (threadIdx.x >> 5);
  int lane32 = threadIdx.x & 31;
  int sub = lane32 >> 4, lane = lane32 & 15;
  if (gid < N) {
    int node = perm[N - 1 - gid];
    float4 i4 = h4f(h2[(long long)node * 16 + lane]);
    float2 brn = br[node], bln = bl[node];
    bool hiH = (lane & 8) != 0;
    float brh = hiH ? brn.y : brn.x;
    float s0 = 0.f, s1 = 0.f;
    float4 v = {0.f, 0.f, 0.f, 0.f};
    // self-loop (j == i): only subgroup 0, to avoid double-count after combine
    if (sub == 0) gat_edge(i4, i4, hiH, bln.x, bln.y, brh, s0, s1, v);
    int beg = rptr[node], end = rptr[node + 1];
    for (int base = beg + sub * 16; base < end; base += 32) {
      int rem = end - base;
      int sj = 0; float bx = 0.f, by = 0.f;
      if (lane < rem) {
        sj = eg[base + lane].x;
        float2 b2 = bl[sj];
        bx = b2.x; by = b2.y;
      }
      if (rem >= 16) {
#pragma unroll
        for (int p = 0; p < 4; ++p) {
          int q0 = p * 4, q1 = q0 + 1, q2 = q0 + 2, q3 = q0 + 3;
          int sA = __shfl(sj, q0, 16);
          int sB = __shfl(sj, q1, 16);
          int sC = __shfl(sj, q2, 16);
          int sD = __shfl(sj, q3, 16);
          int2 rA = h2[(long long)sA * 16 + lane];
          int2 rB = h2[(long long)sB * 16 + lane];
          int2 rC = h2[(long long)sC * 16 + lane];
          int2 rD = h2[(long long)sD * 16 + lane];
          float bxA = __shfl(bx, q0, 16), byA = __shfl(by, q0, 16);
          float bxB = __shfl(bx, q1, 16), byB = __shfl(by, q1, 16);
          float bxC = __shfl(bx, q2, 16), byC = __shfl(by, q2, 16);
          float bxD = __shfl(bx, q3, 16), byD = __shfl(by, q3, 16);
          gat_edge(h4f(rA), i4, hiH, bxA, byA, brh, s0, s1, v);
          gat_edge(h4f(rB), i4, hiH, bxB, byB, brh, s0, s1, v);
          gat_edge(h4f(rC), i4, hiH, bxC, byC, brh, s0, s1, v);
          gat_edge(h4f(rD), i4, hiH, bxD, byD, brh, s0, s1, v);
        }
      } else {
        int q = 0;
        for (; q + 2 <= rem; q += 2) {
          int sA = __shfl(sj, q, 16);
          int sB = __shfl(sj, q + 1, 16);
          int2 rA = h2[(long long)sA * 16 + lane];
          int2 rB = h2[(long long)sB * 16 + lane];
          float bxA = __shfl(bx, q, 16), byA = __shfl(by, q, 16);
          float bxB = __shfl(bx, q + 1, 16), byB = __shfl(by, q + 1, 16);
          gat_edge(h4f(rA), i4, hiH, bxA, byA, brh, s0, s1, v);
          gat_edge(h4f(rB), i4, hiH, bxB, byB, brh, s0, s1, v);
        }
        if (q < rem) {
          int sA = __shfl(sj, q, 16);
          int2 rA = h2[(long long)sA * 16 + lane];
          float bxA = __shfl(bx, q, 16), byA = __shfl(by, q, 16);
          gat_edge(h4f(rA), i4, hiH, bxA, byA, brh, s0, s1, v);
        }
      }
    }
    // combine subgroups (xor16 within the 32-lane node slice)
    s0 += __shfl_xor(s0, 16, 32);
    s1 += __shfl_xor(s1, 16, 32);
    v.x += __shfl_xor(v.x, 16, 32);
    v.y += __shfl_xor(v.y, 16, 32);
    v.z += __shfl_xor(v.z, 16, 32);
    v.w += __shfl_xor(v.w, 16, 32);
    if (sub == 0) {
      float x2a = 0.5f * (v.x / s0 + v.z / s1) + gb[lane];
      float x2b = 0.5f * (v.y / s0 + v.w / s1) + gb[lane + 16];
      float ya = ((x2a > 0.f) ? x2a : 0.01f * x2a) + x2a;
      float yb = ((x2b > 0.f) ? x2b : 0.01f * x2b) + x2b;
      y[(long long)node * 32 + lane] = ya;
      y[(long long)node * 32 + lane + 16] = yb;
      atomicAdd(&ls[lane], ya);
      atomicAdd(&ls[lane + 16], yb);
      atomicAdd(&ls[32 + lane], ya * ya);
      atomicAdd(&ls[32 + lane + 16], yb * yb);
    }
  }
  __syncthreads();
  if (threadIdx.x < 64) atomicAdd(&bns[threadIdx.x], ls[threadIdx.x]);
}

// in-place safe (y may alias out)
__global__ void k_bnfinal(const float* __restrict__ y, const float* __restrict__ bns,
                          const float* __restrict__ g, const float* __restrict__ b,
                          float* __restrict__ out, int N) {
  int i = blockIdx.x * blockDim.x + threadIdx.x;
  if (i >= N * CC) return;
  int c = i & 31;
  float inv_n = 1.f / (float)N;
  float mu = bns[c] * inv_n;
  float var = bns[32 + c] * inv_n - mu * mu;
  out[i] = (y[i] - mu) * rsqrtf(var + 1e-5f) * g[c] + b[c];
}

extern "C" void kernel_launch(void* const* d_in, const int* in_sizes, int n_in,
                              void* d_out, int out_size, void* d_ws, size_t ws_size,
                              hipStream_t stream) {
  const float* patch = (const float*)d_in[0];
  const int* eidx = (const int*)d_in[1];
  // d_in[2] = edge_attr (unused by reference)
  const float* cheb_w = (const float*)d_in[3];
  const float* cheb_b = (const float*)d_in[4];
  const float* lin_w = (const float*)d_in[5];
  const float* att_l = (const float*)d_in[6];
  const float* att_r = (const float*)d_in[7];
  const float* gat_b = (const float*)d_in[8];
  const float* bn_g = (const float*)d_in[9];
  const float* bn_b = (const float*)d_in[10];
  float* out = (float*)d_out;

  const int N = in_sizes[0] / CC;   // 100000
  const int E = in_sizes[1] / 2;    // 1600000
  const int* src = eidx;
  const int* dst = eidx + E;

  // workspace layout (~48 MB); 16B alignment where float4 is used
  float* R0 = (float*)d_ws;                  // N*32 (Tx ping; h-half overlays R0)
  float* R1 = R0 + (size_t)N * 32;           // N*32 (Tx pong)
  int2* eg = (int2*)(R1 + (size_t)N * 32);   // E int2 (edge src + cheb weight)
  int* grptr = (int*)(eg + E);               // N+2 ints (CSR row ptr)
  int* cnt = grptr + (N + 2);                // N ints (in-degree)
  int* csum = cnt + N;                       // 64 ints (chunk sums)
  float* dis = (float*)(csum + 64);          // N floats
  float* bns = dis + N;                      // 64 floats [zeroed]
  int* perm = (int*)(bns + 64);              // N ints (degree-sorted nodes)
  float* bl = (float*)(perm + N);            // N*2 floats (h . att_l per head)
  float* br = bl + (size_t)N * 2;            // N*2 floats (h . att_r per head)
  int* priv = (int*)(br + (size_t)N * 2);    // NCPY*N ints (packed counts) [zeroed]
  int* histmat = priv + (size_t)NCPY * N;    // nbred*64 ints
  __half* h = (__half*)R0;                   // N*64 halves overlays R0 after cheb

  const int B = 256;
  const long long NC = (long long)N * 32;
  int nbred = cdiv(N, REDB);

  hipMemsetAsync(priv, 0, sizeof(int) * (size_t)NCPY * N, stream);
  hipMemsetAsync(bns, 0, sizeof(float) * 64, stream);

  // privatized packed degree counts (16 copies)
  k_cnt<<<cdiv(E, B), B, 0, stream>>>(src, dst, priv, E, N);
  // reduce: dis + cnt + per-copy cursor bases + per-block degree hist
  k_reduce<<<nbred, REDB, 0, stream>>>(priv, dis, cnt, histmat, N);
  // counting-sort bases, then atomic-free permfill
  k_scanhist2<<<1, 64, 0, stream>>>(histmat, nbred);
  k_permfill2<<<nbred, REDB, 0, stream>>>(cnt, histmat, perm, N);

  // CSR rptr over E real edges
  int nb = cdiv(N, CHUNK);
  k_chunksum<<<nb, B, 0, stream>>>(cnt, csum, N);
  k_scancsum<<<1, 1, 0, stream>>>(csum, nb, grptr, N, E);
  k_fillrptr<<<nb, B, 0, stream>>>(cnt, csum, grptr, N);
  // fill interleaved edge records (privatized cursors; same copy map as k_cnt)
  k_fill3<<<cdiv(E, B), B, 0, stream>>>(src, dst, dis, grptr, priv, eg, E, N);

  // ChebConv into d_out: k=0 dense (+bias), k=1..4 fused gather+recurrence+GEMM
  k_gemm32b<<<cdiv(N, 8), B, 0, stream>>>(patch, cheb_w, cheb_b, out, N);
  k_cheb4<<<cdiv(N, 16), B, 0, stream>>>((const float4*)patch, nullptr, grptr, eg,
                                         cheb_w + 1024, perm, 1.f,
                                         (float4*)R0, (float4*)out, N);
  k_cheb4<<<cdiv(N, 16), B, 0, stream>>>((const float4*)R0, (const float4*)patch,
                                         grptr, eg, cheb_w + 2048, perm, 2.f,
                                         (float4*)R1, (float4*)out, N);
  k_cheb4<<<cdiv(N, 16), B, 0, stream>>>((const float4*)R1, (const float4*)R0,
                                         grptr, eg, cheb_w + 3072, perm, 2.f,
                                         (float4*)R0, (float4*)out, N);
  k_cheb4<<<cdiv(N, 16), B, 0, stream>>>((const float4*)R0, (const float4*)R1,
                                         grptr, eg, cheb_w + 4096, perm, 2.f,
                                         nullptr, (float4*)out, N);

  // SuperGAT: h (fp16 head-packed) = x @ lin_w + per-node attention scalars,
  // then fused no-max-softmax gather + epilogue + BN stats
  k_gemmh<<<cdiv(N, 4), B, 0, stream>>>(out, lin_w, att_l, att_r, h, bl, br, N);
  k_expgat4<<<cdiv(N, 8), B, 0, stream>>>((const int2*)h, grptr, eg,
                                          (const float2*)bl, (const float2*)br,
                                          gat_b, perm, out, bns, N);
  k_bnfinal<<<cdiv(NC, B), B, 0, stream>>>(out, bns, bn_g, bn_b, out, N);
}

// Round 11
// 708.121 us; speedup vs baseline: 1.1542x; 1.1542x over previous
//
#include <hip/hip_runtime.h>
#include <hip/hip_fp16.h>
#include <math.h>

#define CC 32
#define CHUNK 4096   // 256 threads * 16 elems, for the rptr scan
#define NCPY 16      // atomic privatization copies
#define REDB 1024    // block size for reduce/permfill (must match between them)

static inline int cdiv(long long a, int b) { return (int)((a + b - 1) / b); }

// unpack 4 halves (int2) -> float4
__device__ inline float4 h4f(int2 r) {
  __half2 lo = *reinterpret_cast<__half2*>(&r.x);
  __half2 hi = *reinterpret_cast<__half2*>(&r.y);
  float2 a = __half22float2(lo), b = __half22float2(hi);
  return make_float4(a.x, a.y, b.x, b.y);
}

// ---------- packed privatized degree count ----------
__global__ void k_cnt(const int* __restrict__ src, const int* __restrict__ dst,
                      int* __restrict__ priv, int E, int N) {
  int e = blockIdx.x * blockDim.x + threadIdx.x;
  if (e >= E) return;
  int* p = priv + (size_t)(blockIdx.x & (NCPY - 1)) * N;
  atomicAdd(&p[src[e]], 1 << 16);
  atomicAdd(&p[dst[e]], 1);
}

// per node: sum copies -> deg (->dis), cnt; rewrite priv to per-copy exclusive
// cursor bases; per-block degree histogram -> histmat[block][64]
__global__ void k_reduce(int* __restrict__ priv, float* __restrict__ dis,
                         int* __restrict__ cnt, int* __restrict__ histmat, int N) {
  __shared__ int lh[64];
  if (threadIdx.x < 64) lh[threadIdx.x] = 0;
  __syncthreads();
  int n = blockIdx.x * REDB + threadIdx.x;
  if (n < N) {
    int vals[NCPY];
    int tot = 0;
#pragma unroll
    for (int c = 0; c < NCPY; ++c) {
      vals[c] = priv[(size_t)c * N + n];
      tot += vals[c];
    }
    int deg = tot >> 16, cv = tot & 0xFFFF;
    dis[n] = (deg > 0) ? rsqrtf((float)deg) : 0.f;
    cnt[n] = cv;
    int acc = 0;
#pragma unroll
    for (int c = 0; c < NCPY; ++c) {
      priv[(size_t)c * N + n] = acc;
      acc += vals[c] & 0xFFFF;
    }
    atomicAdd(&lh[min(cv, 63)], 1);
  }
  __syncthreads();
  if (threadIdx.x < 64) histmat[blockIdx.x * 64 + threadIdx.x] = lh[threadIdx.x];
}

// column scan: histmat[b][bin] -> absolute base of (block b, bin) in perm
__global__ void k_scanhist2(int* __restrict__ histmat, int nb) {
  int lane = threadIdx.x;  // 0..63
  int tot = 0;
  for (int i = 0; i < nb; ++i) tot += histmat[i * 64 + lane];
  __shared__ int sh[64], pf[64];
  sh[lane] = tot;
  __syncthreads();
  if (lane == 0) {
    int acc = 0;
    for (int b = 0; b < 64; ++b) { pf[b] = acc; acc += sh[b]; }
  }
  __syncthreads();
  int acc = pf[lane];
  for (int i = 0; i < nb; ++i) {
    int v = histmat[i * 64 + lane];
    histmat[i * 64 + lane] = acc;
    acc += v;
  }
}

// no global atomics: LDS rank + precomputed per-(block,bin) base
__global__ void k_permfill2(const int* __restrict__ cnt, const int* __restrict__ histmat,
                            int* __restrict__ perm, int N) {
  __shared__ int lh[64], lbase[64];
  if (threadIdx.x < 64) lh[threadIdx.x] = 0;
  __syncthreads();
  int i = blockIdx.x * REDB + threadIdx.x;
  int bin = 0, rank = 0;
  bool act = (i < N);
  if (act) {
    bin = min(cnt[i], 63);
    rank = atomicAdd(&lh[bin], 1);
  }
  __syncthreads();
  if (threadIdx.x < 64) lbase[threadIdx.x] = histmat[blockIdx.x * 64 + threadIdx.x];
  __syncthreads();
  if (act) perm[lbase[bin] + rank] = i;
}

// ---------- CSR rptr: chunk sums -> serial chunk scan -> per-chunk fill ----------
__global__ void k_chunksum(const int* __restrict__ cnt, int* __restrict__ csum, int N) {
  int base = blockIdx.x * CHUNK;
  int v = 0;
  for (int i = threadIdx.x; i < CHUNK; i += 256) {
    int idx = base + i;
    if (idx < N) v += cnt[idx];
  }
  for (int m = 32; m; m >>= 1) v += __shfl_xor(v, m);
  __shared__ int ws[4];
  if ((threadIdx.x & 63) == 0) ws[threadIdx.x >> 6] = v;
  __syncthreads();
  if (threadIdx.x == 0) csum[blockIdx.x] = ws[0] + ws[1] + ws[2] + ws[3];
}

__global__ void k_scancsum(int* __restrict__ csum, int nb, int* __restrict__ rptr,
                           int N, int tot) {
  int acc = 0;
  for (int i = 0; i < nb; ++i) { int v = csum[i]; csum[i] = acc; acc += v; }
  rptr[N] = tot;
}

__global__ void k_fillrptr(int* __restrict__ cnt, const int* __restrict__ csum,
                           int* __restrict__ rptr, int N) {
  int base = blockIdx.x * CHUNK + threadIdx.x * 16;
  int v[16];
  int tot = 0;
#pragma unroll
  for (int q = 0; q < 16; ++q) {
    int idx = base + q;
    v[q] = (idx < N) ? cnt[idx] : 0;
    tot += v[q];
  }
  __shared__ int sh[256];
  sh[threadIdx.x] = tot;
  __syncthreads();
  for (int off = 1; off < 256; off <<= 1) {
    int add = (threadIdx.x >= off) ? sh[threadIdx.x - off] : 0;
    __syncthreads();
    sh[threadIdx.x] += add;
    __syncthreads();
  }
  int excl = sh[threadIdx.x] - tot + csum[blockIdx.x];
#pragma unroll
  for (int q = 0; q < 16; ++q) {
    int idx = base + q;
    if (idx < N) rptr[idx] = excl;
    excl += v[q];
  }
}

// fill interleaved edge records eg[slot] = {src, bits(-dis*dis)}
__global__ void k_fill3(const int* __restrict__ src, const int* __restrict__ dst,
                        const float* __restrict__ dis, const int* __restrict__ rptr,
                        int* __restrict__ priv, int2* __restrict__ eg, int E, int N) {
  int e = blockIdx.x * blockDim.x + threadIdx.x;
  if (e >= E) return;
  int s = src[e], d = dst[e];
  int* pc = priv + (size_t)(blockIdx.x & (NCPY - 1)) * N;
  int p = rptr[d] + atomicAdd(&pc[d], 1);
  int2 v;
  v.x = s;
  v.y = __float_as_int(-dis[s] * dis[d]);
  eg[p] = v;
}

// f32 -> f16 convert (patch shadow)
__global__ void k_half(const float* __restrict__ in, __half* __restrict__ o, int n) {
  int i = blockIdx.x * blockDim.x + threadIdx.x;
  if (i < n) o[i] = __float2half(in[i]);
}

// ---------- fused Cheb step: fp16 gather-prop + f32 recurrence + out += Tx@W ----
// one 8-lane group per node (lane = 4 channels, int2 = 4 halves = 8B/lane);
// LPT perm (heaviest first). Writes f32 Tx (recurrence) + f16 Tx (next gather).
__global__ void k_cheb4(const int2* __restrict__ x_in2,
                        const float4* __restrict__ x_sub4,
                        const int* __restrict__ rptr, const int2* __restrict__ eg,
                        const float* __restrict__ W, const int* __restrict__ perm,
                        float scale, float4* __restrict__ tx_out4,
                        int2* __restrict__ tx_outh, float4* __restrict__ out4,
                        int N) {
  __shared__ float wl[1024];
  for (int i = threadIdx.x; i < 1024; i += 256) wl[i] = W[i];
  __syncthreads();
  int gid = blockIdx.x * 32 + (threadIdx.x >> 3);
  int lane = threadIdx.x & 7;
  if (gid >= N) return;
  int node = perm[N - 1 - gid];
  int beg = rptr[node], end = rptr[node + 1];
  float tx = 0.f, ty = 0.f, tz = 0.f, tw = 0.f;
  for (int base = beg; base < end; base += 8) {
    int rem = end - base;
    int sj = 0; float wjv = 0.f;
    if (lane < rem) {
      int2 v = eg[base + lane];
      sj = v.x;
      wjv = __int_as_float(v.y);
    }
    if (rem >= 8) {
#pragma unroll
      for (int q = 0; q < 8; ++q) {
        int s = __shfl(sj, q, 8);
        float w = __shfl(wjv, q, 8);
        float4 j4 = h4f(x_in2[(long long)s * 8 + lane]);
        tx += w * j4.x; ty += w * j4.y; tz += w * j4.z; tw += w * j4.w;
      }
    } else {
      for (int q = 0; q < rem; ++q) {
        int s = __shfl(sj, q, 8);
        float w = __shfl(wjv, q, 8);
        float4 j4 = h4f(x_in2[(long long)s * 8 + lane]);
        tx += w * j4.x; ty += w * j4.y; tz += w * j4.z; tw += w * j4.w;
      }
    }
  }
  long long o = (long long)node * 8 + lane;
  float ta[4] = {scale * tx, scale * ty, scale * tz, scale * tw};
  if (x_sub4) {
    float4 s4 = x_sub4[o];
    ta[0] -= s4.x; ta[1] -= s4.y; ta[2] -= s4.z; ta[3] -= s4.w;
  }
  if (tx_out4) {
    float4 t4 = {ta[0], ta[1], ta[2], ta[3]};
    tx_out4[o] = t4;
  }
  if (tx_outh) {
    __half hp[4] = {__float2half(ta[0]), __float2half(ta[1]),
                    __float2half(ta[2]), __float2half(ta[3])};
    tx_outh[o] = *reinterpret_cast<int2*>(hp);
  }
  float4 a4 = out4[o];  // issue early; accumulate below
  float ax = 0.f, ay = 0.f, az = 0.f, aw = 0.f;
#pragma unroll
  for (int c = 0; c < 32; ++c) {
    float bc = __shfl(ta[c & 3], c >> 2, 8);
    const float4 w4 = *(const float4*)&wl[c * 32 + lane * 4];
    ax += bc * w4.x; ay += bc * w4.y; az += bc * w4.z; aw += bc * w4.w;
  }
  a4.x += ax; a4.y += ay; a4.z += az; a4.w += aw;
  out4[o] = a4;
}

// out[row][col] = T[row][:] @ W[32][32] + bias[col]   (k=0 term, init)
__global__ void k_gemm32b(const float* __restrict__ T, const float* __restrict__ W,
                          const float* __restrict__ bias, float* __restrict__ out,
                          int N) {
  __shared__ float w[1024];
  for (int i = threadIdx.x; i < 1024; i += 256) w[i] = W[i];
  __syncthreads();
  int row = blockIdx.x * 8 + (threadIdx.x >> 5);
  int col = threadIdx.x & 31;
  if (row >= N) return;
  const float* tr = T + (long long)row * 32;
  float acc = 0.f;
#pragma unroll
  for (int c = 0; c < 32; ++c) acc += tr[c] * w[c * 32 + col];
  out[(long long)row * 32 + col] = acc + bias[col];
}

// h = x @ lin_w stored head-packed HALF: lane l in [0,16) of a row holds
// halves {h0[l], h0[l+16], h1[l], h1[l+16]} (8B/lane, 128B/row). Also
// bl = h.att_l, br = h.att_r (f32, float2 over heads). One wave per row.
__global__ void k_gemmh(const float* __restrict__ T, const float* __restrict__ W,
                        const float* __restrict__ attl, const float* __restrict__ attr,
                        __half* __restrict__ h, float* __restrict__ bl,
                        float* __restrict__ br, int N) {
  __shared__ float w[2048];
  for (int i = threadIdx.x; i < 2048; i += 256) w[i] = W[i];
  __syncthreads();
  int row = blockIdx.x * 4 + (threadIdx.x >> 6);
  int col = threadIdx.x & 63;
  if (row >= N) return;
  const float* tr = T + (long long)row * 32;
  float acc = 0.f;
#pragma unroll
  for (int c = 0; c < 32; ++c) acc += tr[c] * w[c * 64 + col];
  int ch = col & 31, hd = col >> 5;
  h[(long long)row * 64 + (ch & 15) * 4 + (ch >> 4) + 2 * hd] = __float2half(acc);
  float pl = acc * attl[col], pr = acc * attr[col];
#pragma unroll
  for (int m = 16; m; m >>= 1) {
    pl += __shfl_xor(pl, m, 64);
    pr += __shfl_xor(pr, m, 64);
  }
  if ((col & 31) == 0) {
    bl[row * 2 + (col >> 5)] = pl;
    br[row * 2 + (col >> 5)] = pr;
  }
}

// ---------- fused SuperGAT: 16-lane groups (R9 structure), fp16 head-packed h,
// head-split butterfly, no-max softmax, in-register self-loop, 4-way
// interleaved, LPT perm. Epilogue: bias+head-mean+leaky+res+BN partials.
__device__ inline void gat_edge(const float4& j4, const float4& i4, bool hiH,
                                float bxq, float byq, float brh,
                                float& s0, float& s1, float4& v) {
  float d0 = j4.x * i4.x + j4.y * i4.y;
  float d1 = j4.z * i4.z + j4.w * i4.w;
  d0 += __shfl_xor(d0, 8, 16);
  d1 += __shfl_xor(d1, 8, 16);
  float dc = hiH ? d1 : d0;
  dc += __shfl_xor(dc, 4, 16);
  dc += __shfl_xor(dc, 2, 16);
  dc += __shfl_xor(dc, 1, 16);
  float lin = (hiH ? byq : bxq) + brh;
  float a = lin / (1.f + __expf(-dc));
  a = (a > 0.f) ? a : 0.2f * a;
  float ec = __expf(a);
  float e0 = __shfl(ec, 0, 16), e1 = __shfl(ec, 8, 16);
  s0 += e0; s1 += e1;
  v.x += e0 * j4.x; v.y += e0 * j4.y; v.z += e1 * j4.z; v.w += e1 * j4.w;
}

__global__ void k_expgat4(const int2* __restrict__ h2, const int* __restrict__ rptr,
                          const int2* __restrict__ eg, const float2* __restrict__ bl,
                          const float2* __restrict__ br, const float* __restrict__ gb,
                          const int* __restrict__ perm, float* __restrict__ y,
                          float* __restrict__ bns, int N) {
  __shared__ float ls[64];
  for (int i = threadIdx.x; i < 64; i += 256) ls[i] = 0.f;
  __syncthreads();
  int gid = blockIdx.x * 16 + (threadIdx.x >> 4);
  int lane = threadIdx.x & 15;
  if (gid < N) {
    int node = perm[N - 1 - gid];
    float4 i4 = h4f(h2[(long long)node * 16 + lane]);
    float2 brn = br[node], bln = bl[node];
    bool hiH = (lane & 8) != 0;
    float brh = hiH ? brn.y : brn.x;
    float s0 = 0.f, s1 = 0.f;
    float4 v = {0.f, 0.f, 0.f, 0.f};
    // self-loop (j == i)
    gat_edge(i4, i4, hiH, bln.x, bln.y, brh, s0, s1, v);
    int beg = rptr[node], end = rptr[node + 1];
    for (int base = beg; base < end; base += 16) {
      int rem = end - base;
      int sj = 0; float bx = 0.f, by = 0.f;
      if (lane < rem) {
        sj = eg[base + lane].x;
        float2 b2 = bl[sj];
        bx = b2.x; by = b2.y;
      }
      if (rem >= 16) {
#pragma unroll
        for (int p = 0; p < 4; ++p) {
          int q0 = p * 4, q1 = q0 + 1, q2 = q0 + 2, q3 = q0 + 3;
          int sA = __shfl(sj, q0, 16);
          int sB = __shfl(sj, q1, 16);
          int sC = __shfl(sj, q2, 16);
          int sD = __shfl(sj, q3, 16);
          int2 rA = h2[(long long)sA * 16 + lane];
          int2 rB = h2[(long long)sB * 16 + lane];
          int2 rC = h2[(long long)sC * 16 + lane];
          int2 rD = h2[(long long)sD * 16 + lane];
          float bxA = __shfl(bx, q0, 16), byA = __shfl(by, q0, 16);
          float bxB = __shfl(bx, q1, 16), byB = __shfl(by, q1, 16);
          float bxC = __shfl(bx, q2, 16), byC = __shfl(by, q2, 16);
          float bxD = __shfl(bx, q3, 16), byD = __shfl(by, q3, 16);
          gat_edge(h4f(rA), i4, hiH, bxA, byA, brh, s0, s1, v);
          gat_edge(h4f(rB), i4, hiH, bxB, byB, brh, s0, s1, v);
          gat_edge(h4f(rC), i4, hiH, bxC, byC, brh, s0, s1, v);
          gat_edge(h4f(rD), i4, hiH, bxD, byD, brh, s0, s1, v);
        }
      } else {
        int q = 0;
        for (; q + 2 <= rem; q += 2) {
          int sA = __shfl(sj, q, 16);
          int sB = __shfl(sj, q + 1, 16);
          int2 rA = h2[(long long)sA * 16 + lane];
          int2 rB = h2[(long long)sB * 16 + lane];
          float bxA = __shfl(bx, q, 16), byA = __shfl(by, q, 16);
          float bxB = __shfl(bx, q + 1, 16), byB = __shfl(by, q + 1, 16);
          gat_edge(h4f(rA), i4, hiH, bxA, byA, brh, s0, s1, v);
          gat_edge(h4f(rB), i4, hiH, bxB, byB, brh, s0, s1, v);
        }
        if (q < rem) {
          int sA = __shfl(sj, q, 16);
          int2 rA = h2[(long long)sA * 16 + lane];
          float bxA = __shfl(bx, q, 16), byA = __shfl(by, q, 16);
          gat_edge(h4f(rA), i4, hiH, bxA, byA, brh, s0, s1, v);
        }
      }
    }
    float x2a = 0.5f * (v.x / s0 + v.z / s1) + gb[lane];
    float x2b = 0.5f * (v.y / s0 + v.w / s1) + gb[lane + 16];
    float ya = ((x2a > 0.f) ? x2a : 0.01f * x2a) + x2a;
    float yb = ((x2b > 0.f) ? x2b : 0.01f * x2b) + x2b;
    y[(long long)node * 32 + lane] = ya;
    y[(long long)node * 32 + lane + 16] = yb;
    atomicAdd(&ls[lane], ya);
    atomicAdd(&ls[lane + 16], yb);
    atomicAdd(&ls[32 + lane], ya * ya);
    atomicAdd(&ls[32 + lane + 16], yb * yb);
  }
  __syncthreads();
  if (threadIdx.x < 64) atomicAdd(&bns[threadIdx.x], ls[threadIdx.x]);
}

// in-place safe (y may alias out)
__global__ void k_bnfinal(const float* __restrict__ y, const float* __restrict__ bns,
                          const float* __restrict__ g, const float* __restrict__ b,
                          float* __restrict__ out, int N) {
  int i = blockIdx.x * blockDim.x + threadIdx.x;
  if (i >= N * CC) return;
  int c = i & 31;
  float inv_n = 1.f / (float)N;
  float mu = bns[c] * inv_n;
  float var = bns[32 + c] * inv_n - mu * mu;
  out[i] = (y[i] - mu) * rsqrtf(var + 1e-5f) * g[c] + b[c];
}

extern "C" void kernel_launch(void* const* d_in, const int* in_sizes, int n_in,
                              void* d_out, int out_size, void* d_ws, size_t ws_size,
                              hipStream_t stream) {
  const float* patch = (const float*)d_in[0];
  const int* eidx = (const int*)d_in[1];
  // d_in[2] = edge_attr (unused by reference)
  const float* cheb_w = (const float*)d_in[3];
  const float* cheb_b = (const float*)d_in[4];
  const float* lin_w = (const float*)d_in[5];
  const float* att_l = (const float*)d_in[6];
  const float* att_r = (const float*)d_in[7];
  const float* gat_b = (const float*)d_in[8];
  const float* bn_g = (const float*)d_in[9];
  const float* bn_b = (const float*)d_in[10];
  float* out = (float*)d_out;

  const int N = in_sizes[0] / CC;   // 100000
  const int E = in_sizes[1] / 2;    // 1600000
  const int* src = eidx;
  const int* dst = eidx + E;

  // workspace layout (~61 MB); 16B alignment where float4 is used
  float* R0 = (float*)d_ws;                  // N*32 f32 (Tx ping; h overlays R0)
  float* R1 = R0 + (size_t)N * 32;           // N*32 f32 (Tx pong)
  int2* eg = (int2*)(R1 + (size_t)N * 32);   // E int2 (edge src + cheb weight)
  int* grptr = (int*)(eg + E);               // N+2 ints (CSR row ptr)
  int* cnt = grptr + (N + 2);                // N ints (in-degree)
  int* csum = cnt + N;                       // 64 ints (chunk sums)
  float* dis = (float*)(csum + 64);          // N floats
  float* bns = dis + N;                      // 64 floats [zeroed]
  int* perm = (int*)(bns + 64);              // N ints (degree-sorted nodes)
  float* bl = (float*)(perm + N);            // N*2 floats (h . att_l per head)
  float* br = bl + (size_t)N * 2;            // N*2 floats (h . att_r per head)
  int* priv = (int*)(br + (size_t)N * 2);    // NCPY*N ints (counts) [zeroed]
  int* histmat = priv + (size_t)NCPY * N;    // nbred*64 ints
  int2* Ha = (int2*)(histmat + 64 * 128);    // N*8 int2 (fp16 Tx shadow A)
  int2* Hb = Ha + (size_t)N * 8;             // N*8 int2 (fp16 Tx shadow B)
  __half* pf16 = (__half*)priv;              // N*32 halves overlays priv after fill3
  __half* h = (__half*)R0;                   // N*64 halves overlays R0 after cheb

  const int B = 256;
  const long long NC = (long long)N * 32;
  int nbred = cdiv(N, REDB);

  hipMemsetAsync(priv, 0, sizeof(int) * (size_t)NCPY * N, stream);
  hipMemsetAsync(bns, 0, sizeof(float) * 64, stream);

  // privatized packed degree counts (16 copies)
  k_cnt<<<cdiv(E, B), B, 0, stream>>>(src, dst, priv, E, N);
  // reduce: dis + cnt + per-copy cursor bases + per-block degree hist
  k_reduce<<<nbred, REDB, 0, stream>>>(priv, dis, cnt, histmat, N);
  // counting-sort bases, then atomic-free permfill
  k_scanhist2<<<1, 64, 0, stream>>>(histmat, nbred);
  k_permfill2<<<nbred, REDB, 0, stream>>>(cnt, histmat, perm, N);

  // CSR rptr over E real edges
  int nb = cdiv(N, CHUNK);
  k_chunksum<<<nb, B, 0, stream>>>(cnt, csum, N);
  k_scancsum<<<1, 1, 0, stream>>>(csum, nb, grptr, N, E);
  k_fillrptr<<<nb, B, 0, stream>>>(cnt, csum, grptr, N);
  // fill interleaved edge records (privatized cursors; same copy map as k_cnt)
  k_fill3<<<cdiv(E, B), B, 0, stream>>>(src, dst, dis, grptr, priv, eg, E, N);
  // patch fp16 shadow (priv is dead now; pf16 overlays it)
  k_half<<<cdiv(NC, B), B, 0, stream>>>(patch, pf16, N * 32);

  // ChebConv into d_out: k=0 dense (+bias), k=1..4 fused fp16-gather + f32
  // recurrence + GEMM. f16 shadows: pf16 -> Ha -> Hb -> Ha.
  k_gemm32b<<<cdiv(N, 8), B, 0, stream>>>(patch, cheb_w, cheb_b, out, N);
  k_cheb4<<<cdiv(N, 32), B, 0, stream>>>((const int2*)pf16, nullptr, grptr, eg,
                                         cheb_w + 1024, perm, 1.f,
                                         (float4*)R0, Ha, (float4*)out, N);
  k_cheb4<<<cdiv(N, 32), B, 0, stream>>>(Ha, (const float4*)patch, grptr, eg,
                                         cheb_w + 2048, perm, 2.f,
                                         (float4*)R1, Hb, (float4*)out, N);
  k_cheb4<<<cdiv(N, 32), B, 0, stream>>>(Hb, (const float4*)R0, grptr, eg,
                                         cheb_w + 3072, perm, 2.f,
                                         (float4*)R0, Ha, (float4*)out, N);
  k_cheb4<<<cdiv(N, 32), B, 0, stream>>>(Ha, (const float4*)R1, grptr, eg,
                                         cheb_w + 4096, perm, 2.f,
                                         nullptr, nullptr, (float4*)out, N);

  // SuperGAT: h (fp16 head-packed) = x @ lin_w + per-node attention scalars,
  // then fused no-max-softmax gather + epilogue + BN stats
  k_gemmh<<<cdiv(N, 4), B, 0, stream>>>(out, lin_w, att_l, att_r, h, bl, br, N);
  k_expgat4<<<cdiv(N, 16), B, 0, stream>>>((const int2*)h, grptr, eg,
                                           (const float2*)bl, (const float2*)br,
                                           gat_b, perm, out, bns, N);
  k_bnfinal<<<cdiv(NC, B), B, 0, stream>>>(out, bns, bn_g, bn_b, out, N);
}

// Round 12
// 692.153 us; speedup vs baseline: 1.1809x; 1.0231x over previous
//
#include <hip/hip_runtime.h>
#include <hip/hip_fp16.h>
#include <math.h>

#define CC 32
#define CHUNK 4096   // 256 threads * 16 elems, for the rptr scan
#define NCPY 16      // atomic privatization copies
#define REDB 1024    // block size for reduce/permfill (must match between them)

static inline int cdiv(long long a, int b) { return (int)((a + b - 1) / b); }

// unpack 4 halves (int2) -> float4
__device__ inline float4 h4f(int2 r) {
  __half2 lo = *reinterpret_cast<__half2*>(&r.x);
  __half2 hi = *reinterpret_cast<__half2*>(&r.y);
  float2 a = __half22float2(lo), b = __half22float2(hi);
  return make_float4(a.x, a.y, b.x, b.y);
}

// ---------- packed privatized degree count ----------
__global__ void k_cnt(const int* __restrict__ src, const int* __restrict__ dst,
                      int* __restrict__ priv, int E, int N) {
  int e = blockIdx.x * blockDim.x + threadIdx.x;
  if (e >= E) return;
  int* p = priv + (size_t)(blockIdx.x & (NCPY - 1)) * N;
  atomicAdd(&p[src[e]], 1 << 16);
  atomicAdd(&p[dst[e]], 1);
}

// per node: sum copies -> deg (->dis), cnt; rewrite priv to per-copy exclusive
// cursor bases; per-block degree histogram -> histmat[block][64]
__global__ void k_reduce(int* __restrict__ priv, float* __restrict__ dis,
                         int* __restrict__ cnt, int* __restrict__ histmat, int N) {
  __shared__ int lh[64];
  if (threadIdx.x < 64) lh[threadIdx.x] = 0;
  __syncthreads();
  int n = blockIdx.x * REDB + threadIdx.x;
  if (n < N) {
    int vals[NCPY];
    int tot = 0;
#pragma unroll
    for (int c = 0; c < NCPY; ++c) {
      vals[c] = priv[(size_t)c * N + n];
      tot += vals[c];
    }
    int deg = tot >> 16, cv = tot & 0xFFFF;
    dis[n] = (deg > 0) ? rsqrtf((float)deg) : 0.f;
    cnt[n] = cv;
    int acc = 0;
#pragma unroll
    for (int c = 0; c < NCPY; ++c) {
      priv[(size_t)c * N + n] = acc;
      acc += vals[c] & 0xFFFF;
    }
    atomicAdd(&lh[min(cv, 63)], 1);
  }
  __syncthreads();
  if (threadIdx.x < 64) histmat[blockIdx.x * 64 + threadIdx.x] = lh[threadIdx.x];
}

// column scan: histmat[b][bin] -> absolute base of (block b, bin) in perm
__global__ void k_scanhist2(int* __restrict__ histmat, int nb) {
  int lane = threadIdx.x;  // 0..63
  int tot = 0;
  for (int i = 0; i < nb; ++i) tot += histmat[i * 64 + lane];
  __shared__ int sh[64], pf[64];
  sh[lane] = tot;
  __syncthreads();
  if (lane == 0) {
    int acc = 0;
    for (int b = 0; b < 64; ++b) { pf[b] = acc; acc += sh[b]; }
  }
  __syncthreads();
  int acc = pf[lane];
  for (int i = 0; i < nb; ++i) {
    int v = histmat[i * 64 + lane];
    histmat[i * 64 + lane] = acc;
    acc += v;
  }
}

// no global atomics: LDS rank + precomputed per-(block,bin) base
__global__ void k_permfill2(const int* __restrict__ cnt, const int* __restrict__ histmat,
                            int* __restrict__ perm, int N) {
  __shared__ int lh[64], lbase[64];
  if (threadIdx.x < 64) lh[threadIdx.x] = 0;
  __syncthreads();
  int i = blockIdx.x * REDB + threadIdx.x;
  int bin = 0, rank = 0;
  bool act = (i < N);
  if (act) {
    bin = min(cnt[i], 63);
    rank = atomicAdd(&lh[bin], 1);
  }
  __syncthreads();
  if (threadIdx.x < 64) lbase[threadIdx.x] = histmat[blockIdx.x * 64 + threadIdx.x];
  __syncthreads();
  if (act) perm[lbase[bin] + rank] = i;
}

// ---------- CSR rptr: chunk sums -> serial chunk scan -> per-chunk fill ----------
__global__ void k_chunksum(const int* __restrict__ cnt, int* __restrict__ csum, int N) {
  int base = blockIdx.x * CHUNK;
  int v = 0;
  for (int i = threadIdx.x; i < CHUNK; i += 256) {
    int idx = base + i;
    if (idx < N) v += cnt[idx];
  }
  for (int m = 32; m; m >>= 1) v += __shfl_xor(v, m);
  __shared__ int ws[4];
  if ((threadIdx.x & 63) == 0) ws[threadIdx.x >> 6] = v;
  __syncthreads();
  if (threadIdx.x == 0) csum[blockIdx.x] = ws[0] + ws[1] + ws[2] + ws[3];
}

__global__ void k_scancsum(int* __restrict__ csum, int nb, int* __restrict__ rptr,
                           int N, int tot) {
  int acc = 0;
  for (int i = 0; i < nb; ++i) { int v = csum[i]; csum[i] = acc; acc += v; }
  rptr[N] = tot;
}

__global__ void k_fillrptr(int* __restrict__ cnt, const int* __restrict__ csum,
                           int* __restrict__ rptr, int N) {
  int base = blockIdx.x * CHUNK + threadIdx.x * 16;
  int v[16];
  int tot = 0;
#pragma unroll
  for (int q = 0; q < 16; ++q) {
    int idx = base + q;
    v[q] = (idx < N) ? cnt[idx] : 0;
    tot += v[q];
  }
  __shared__ int sh[256];
  sh[threadIdx.x] = tot;
  __syncthreads();
  for (int off = 1; off < 256; off <<= 1) {
    int add = (threadIdx.x >= off) ? sh[threadIdx.x - off] : 0;
    __syncthreads();
    sh[threadIdx.x] += add;
    __syncthreads();
  }
  int excl = sh[threadIdx.x] - tot + csum[blockIdx.x];
#pragma unroll
  for (int q = 0; q < 16; ++q) {
    int idx = base + q;
    if (idx < N) rptr[idx] = excl;
    excl += v[q];
  }
}

// fill interleaved edge records eg[slot] = {src, bits(-dis*dis)}
__global__ void k_fill3(const int* __restrict__ src, const int* __restrict__ dst,
                        const float* __restrict__ dis, const int* __restrict__ rptr,
                        int* __restrict__ priv, int2* __restrict__ eg, int E, int N) {
  int e = blockIdx.x * blockDim.x + threadIdx.x;
  if (e >= E) return;
  int s = src[e], d = dst[e];
  int* pc = priv + (size_t)(blockIdx.x & (NCPY - 1)) * N;
  int p = rptr[d] + atomicAdd(&pc[d], 1);
  int2 v;
  v.x = s;
  v.y = __float_as_int(-dis[s] * dis[d]);
  eg[p] = v;
}

// ---------- fused Cheb step: f32 gather-prop + recurrence + out += Tx@W ----
// one 8-lane group per node (lane = 4 channels); LPT perm (heaviest first).
__global__ void k_cheb4(const float4* __restrict__ x_in4,
                        const float4* __restrict__ x_sub4,
                        const int* __restrict__ rptr, const int2* __restrict__ eg,
                        const float* __restrict__ W, const int* __restrict__ perm,
                        float scale, float4* __restrict__ tx_out4,
                        float4* __restrict__ out4, int N) {
  __shared__ float wl[1024];
  for (int i = threadIdx.x; i < 1024; i += 256) wl[i] = W[i];
  __syncthreads();
  int gid = blockIdx.x * 32 + (threadIdx.x >> 3);
  int lane = threadIdx.x & 7;
  if (gid >= N) return;
  int node = perm[N - 1 - gid];
  int beg = rptr[node], end = rptr[node + 1];
  float tx = 0.f, ty = 0.f, tz = 0.f, tw = 0.f;
  for (int base = beg; base < end; base += 8) {
    int rem = end - base;
    int sj = 0; float wjv = 0.f;
    if (lane < rem) {
      int2 v = eg[base + lane];
      sj = v.x;
      wjv = __int_as_float(v.y);
    }
    if (rem >= 8) {
#pragma unroll
      for (int q = 0; q < 8; ++q) {
        int s = __shfl(sj, q, 8);
        float w = __shfl(wjv, q, 8);
        float4 j4 = x_in4[(long long)s * 8 + lane];
        tx += w * j4.x; ty += w * j4.y; tz += w * j4.z; tw += w * j4.w;
      }
    } else {
      for (int q = 0; q < rem; ++q) {
        int s = __shfl(sj, q, 8);
        float w = __shfl(wjv, q, 8);
        float4 j4 = x_in4[(long long)s * 8 + lane];
        tx += w * j4.x; ty += w * j4.y; tz += w * j4.z; tw += w * j4.w;
      }
    }
  }
  long long o = (long long)node * 8 + lane;
  float ta[4] = {scale * tx, scale * ty, scale * tz, scale * tw};
  if (x_sub4) {
    float4 s4 = x_sub4[o];
    ta[0] -= s4.x; ta[1] -= s4.y; ta[2] -= s4.z; ta[3] -= s4.w;
  }
  if (tx_out4) {
    float4 t4 = {ta[0], ta[1], ta[2], ta[3]};
    tx_out4[o] = t4;
  }
  float4 a4 = out4[o];  // issue early; accumulate below
  float ax = 0.f, ay = 0.f, az = 0.f, aw = 0.f;
#pragma unroll
  for (int c = 0; c < 32; ++c) {
    float bc = __shfl(ta[c & 3], c >> 2, 8);
    const float4 w4 = *(const float4*)&wl[c * 32 + lane * 4];
    ax += bc * w4.x; ay += bc * w4.y; az += bc * w4.z; aw += bc * w4.w;
  }
  a4.x += ax; a4.y += ay; a4.z += az; a4.w += aw;
  out4[o] = a4;
}

// out[row][col] = T[row][:] @ W[32][32] + bias[col]   (k=0 term, init)
__global__ void k_gemm32b(const float* __restrict__ T, const float* __restrict__ W,
                          const float* __restrict__ bias, float* __restrict__ out,
                          int N) {
  __shared__ float w[1024];
  for (int i = threadIdx.x; i < 1024; i += 256) w[i] = W[i];
  __syncthreads();
  int row = blockIdx.x * 8 + (threadIdx.x >> 5);
  int col = threadIdx.x & 31;
  if (row >= N) return;
  const float* tr = T + (long long)row * 32;
  float acc = 0.f;
#pragma unroll
  for (int c = 0; c < 32; ++c) acc += tr[c] * w[c * 32 + col];
  out[(long long)row * 32 + col] = acc + bias[col];
}

// h = x @ lin_w stored head-packed HALF: lane l in [0,16) of a row holds
// halves {h0[l], h0[l+16], h1[l], h1[l+16]} (8B/lane, 128B/row).
// Pure GEMM + fp16 pack (attention scalars now recomputed in-register by GAT).
__global__ void k_gemmh(const float* __restrict__ T, const float* __restrict__ W,
                        __half* __restrict__ h, int N) {
  __shared__ float w[2048];
  for (int i = threadIdx.x; i < 2048; i += 256) w[i] = W[i];
  __syncthreads();
  int row = blockIdx.x * 4 + (threadIdx.x >> 6);
  int col = threadIdx.x & 63;
  if (row >= N) return;
  const float* tr = T + (long long)row * 32;
  float acc = 0.f;
#pragma unroll
  for (int c = 0; c < 32; ++c) acc += tr[c] * w[c * 64 + col];
  int ch = col & 31, hd = col >> 5;
  h[(long long)row * 64 + (ch & 15) * 4 + (ch >> 4) + 2 * hd] = __float2half(acc);
}

// ---------- fused SuperGAT: 16-lane groups, fp16 head-packed h, head-split
// butterfly carrying BOTH logits and the in-register bl = h[s].att_l term
// (kills the per-edge bl gather -> 1 random request per edge), no-max softmax,
// in-register self-loop + br, 4-way interleaved, LPT perm.
__device__ inline void gat_edge(const float4& j4, const float4& i4, const float4& al,
                                bool hiH, float brh,
                                float& s0, float& s1, float4& v) {
  float d0 = j4.x * i4.x + j4.y * i4.y;
  float d1 = j4.z * i4.z + j4.w * i4.w;
  float b0 = j4.x * al.x + j4.y * al.y;
  float b1 = j4.z * al.z + j4.w * al.w;
  d0 += __shfl_xor(d0, 8, 16);
  d1 += __shfl_xor(d1, 8, 16);
  b0 += __shfl_xor(b0, 8, 16);
  b1 += __shfl_xor(b1, 8, 16);
  float dc = hiH ? d1 : d0;
  float bc = hiH ? b1 : b0;
  dc += __shfl_xor(dc, 4, 16); bc += __shfl_xor(bc, 4, 16);
  dc += __shfl_xor(dc, 2, 16); bc += __shfl_xor(bc, 2, 16);
  dc += __shfl_xor(dc, 1, 16); bc += __shfl_xor(bc, 1, 16);
  float lin = bc + brh;
  float a = lin / (1.f + __expf(-dc));
  a = (a > 0.f) ? a : 0.2f * a;
  float ec = __expf(a);
  float e0 = __shfl(ec, 0, 16), e1 = __shfl(ec, 8, 16);
  s0 += e0; s1 += e1;
  v.x += e0 * j4.x; v.y += e0 * j4.y; v.z += e1 * j4.z; v.w += e1 * j4.w;
}

__global__ void k_expgat4(const int2* __restrict__ h2, const int* __restrict__ rptr,
                          const int2* __restrict__ eg, const float* __restrict__ attl,
                          const float* __restrict__ attr, const float* __restrict__ gb,
                          const int* __restrict__ perm, float* __restrict__ y,
                          float* __restrict__ bns, int N) {
  __shared__ float ls[64];
  for (int i = threadIdx.x; i < 64; i += 256) ls[i] = 0.f;
  __syncthreads();
  int gid = blockIdx.x * 16 + (threadIdx.x >> 4);
  int lane = threadIdx.x & 15;
  // per-lane attention vectors for this lane's 4 channels (head-packed layout)
  float4 al = {attl[lane], attl[lane + 16], attl[32 + lane], attl[48 + lane]};
  float4 ar = {attr[lane], attr[lane + 16], attr[32 + lane], attr[48 + lane]};
  if (gid < N) {
    int node = perm[N - 1 - gid];
    float4 i4 = h4f(h2[(long long)node * 16 + lane]);
    bool hiH = (lane & 8) != 0;
    // br[node] per head, in-register (same head-split butterfly)
    float r0 = i4.x * ar.x + i4.y * ar.y;
    float r1 = i4.z * ar.z + i4.w * ar.w;
    r0 += __shfl_xor(r0, 8, 16);
    r1 += __shfl_xor(r1, 8, 16);
    float brh = hiH ? r1 : r0;
    brh += __shfl_xor(brh, 4, 16);
    brh += __shfl_xor(brh, 2, 16);
    brh += __shfl_xor(brh, 1, 16);
    float s0 = 0.f, s1 = 0.f;
    float4 v = {0.f, 0.f, 0.f, 0.f};
    // self-loop (j == i; bl[node] computed in-register inside gat_edge)
    gat_edge(i4, i4, al, hiH, brh, s0, s1, v);
    int beg = rptr[node], end = rptr[node + 1];
    for (int base = beg; base < end; base += 16) {
      int rem = end - base;
      int sj = 0;
      if (lane < rem) sj = eg[base + lane].x;
      if (rem >= 16) {
#pragma unroll
        for (int p = 0; p < 4; ++p) {
          int q0 = p * 4, q1 = q0 + 1, q2 = q0 + 2, q3 = q0 + 3;
          int sA = __shfl(sj, q0, 16);
          int sB = __shfl(sj, q1, 16);
          int sC = __shfl(sj, q2, 16);
          int sD = __shfl(sj, q3, 16);
          int2 rA = h2[(long long)sA * 16 + lane];
          int2 rB = h2[(long long)sB * 16 + lane];
          int2 rC = h2[(long long)sC * 16 + lane];
          int2 rD = h2[(long long)sD * 16 + lane];
          gat_edge(h4f(rA), i4, al, hiH, brh, s0, s1, v);
          gat_edge(h4f(rB), i4, al, hiH, brh, s0, s1, v);
          gat_edge(h4f(rC), i4, al, hiH, brh, s0, s1, v);
          gat_edge(h4f(rD), i4, al, hiH, brh, s0, s1, v);
        }
      } else {
        int q = 0;
        for (; q + 2 <= rem; q += 2) {
          int sA = __shfl(sj, q, 16);
          int sB = __shfl(sj, q + 1, 16);
          int2 rA = h2[(long long)sA * 16 + lane];
          int2 rB = h2[(long long)sB * 16 + lane];
          gat_edge(h4f(rA), i4, al, hiH, brh, s0, s1, v);
          gat_edge(h4f(rB), i4, al, hiH, brh, s0, s1, v);
        }
        if (q < rem) {
          int sA = __shfl(sj, q, 16);
          int2 rA = h2[(long long)sA * 16 + lane];
          gat_edge(h4f(rA), i4, al, hiH, brh, s0, s1, v);
        }
      }
    }
    float x2a = 0.5f * (v.x / s0 + v.z / s1) + gb[lane];
    float x2b = 0.5f * (v.y / s0 + v.w / s1) + gb[lane + 16];
    float ya = ((x2a > 0.f) ? x2a : 0.01f * x2a) + x2a;
    float yb = ((x2b > 0.f) ? x2b : 0.01f * x2b) + x2b;
    y[(long long)node * 32 + lane] = ya;
    y[(long long)node * 32 + lane + 16] = yb;
    atomicAdd(&ls[lane], ya);
    atomicAdd(&ls[lane + 16], yb);
    atomicAdd(&ls[32 + lane], ya * ya);
    atomicAdd(&ls[32 + lane + 16], yb * yb);
  }
  __syncthreads();
  if (threadIdx.x < 64) atomicAdd(&bns[threadIdx.x], ls[threadIdx.x]);
}

// in-place safe (y may alias out)
__global__ void k_bnfinal(const float* __restrict__ y, const float* __restrict__ bns,
                          const float* __restrict__ g, const float* __restrict__ b,
                          float* __restrict__ out, int N) {
  int i = blockIdx.x * blockDim.x + threadIdx.x;
  if (i >= N * CC) return;
  int c = i & 31;
  float inv_n = 1.f / (float)N;
  float mu = bns[c] * inv_n;
  float var = bns[32 + c] * inv_n - mu * mu;
  out[i] = (y[i] - mu) * rsqrtf(var + 1e-5f) * g[c] + b[c];
}

extern "C" void kernel_launch(void* const* d_in, const int* in_sizes, int n_in,
                              void* d_out, int out_size, void* d_ws, size_t ws_size,
                              hipStream_t stream) {
  const float* patch = (const float*)d_in[0];
  const int* eidx = (const int*)d_in[1];
  // d_in[2] = edge_attr (unused by reference)
  const float* cheb_w = (const float*)d_in[3];
  const float* cheb_b = (const float*)d_in[4];
  const float* lin_w = (const float*)d_in[5];
  const float* att_l = (const float*)d_in[6];
  const float* att_r = (const float*)d_in[7];
  const float* gat_b = (const float*)d_in[8];
  const float* bn_g = (const float*)d_in[9];
  const float* bn_b = (const float*)d_in[10];
  float* out = (float*)d_out;

  const int N = in_sizes[0] / CC;   // 100000
  const int E = in_sizes[1] / 2;    // 1600000
  const int* src = eidx;
  const int* dst = eidx + E;

  // workspace layout (~47 MB); 16B alignment where float4 is used
  float* R0 = (float*)d_ws;                  // N*32 f32 (Tx ping; h overlays R0)
  float* R1 = R0 + (size_t)N * 32;           // N*32 f32 (Tx pong)
  int2* eg = (int2*)(R1 + (size_t)N * 32);   // E int2 (edge src + cheb weight)
  int* grptr = (int*)(eg + E);               // N+2 ints (CSR row ptr)
  int* cnt = grptr + (N + 2);                // N ints (in-degree)
  int* csum = cnt + N;                       // 64 ints (chunk sums)
  float* dis = (float*)(csum + 64);          // N floats
  float* bns = dis + N;                      // 64 floats [zeroed]
  int* perm = (int*)(bns + 64);              // N ints (degree-sorted nodes)
  int* priv = (int*)(perm + N);              // NCPY*N ints (counts) [zeroed]
  int* histmat = priv + (size_t)NCPY * N;    // nbred*64 ints
  __half* h = (__half*)R0;                   // N*64 halves overlays R0 after cheb

  const int B = 256;
  const long long NC = (long long)N * 32;
  int nbred = cdiv(N, REDB);

  hipMemsetAsync(priv, 0, sizeof(int) * (size_t)NCPY * N, stream);
  hipMemsetAsync(bns, 0, sizeof(float) * 64, stream);

  // privatized packed degree counts (16 copies)
  k_cnt<<<cdiv(E, B), B, 0, stream>>>(src, dst, priv, E, N);
  // reduce: dis + cnt + per-copy cursor bases + per-block degree hist
  k_reduce<<<nbred, REDB, 0, stream>>>(priv, dis, cnt, histmat, N);
  // counting-sort bases, then atomic-free permfill
  k_scanhist2<<<1, 64, 0, stream>>>(histmat, nbred);
  k_permfill2<<<nbred, REDB, 0, stream>>>(cnt, histmat, perm, N);

  // CSR rptr over E real edges
  int nb = cdiv(N, CHUNK);
  k_chunksum<<<nb, B, 0, stream>>>(cnt, csum, N);
  k_scancsum<<<1, 1, 0, stream>>>(csum, nb, grptr, N, E);
  k_fillrptr<<<nb, B, 0, stream>>>(cnt, csum, grptr, N);
  // fill interleaved edge records (privatized cursors; same copy map as k_cnt)
  k_fill3<<<cdiv(E, B), B, 0, stream>>>(src, dst, dis, grptr, priv, eg, E, N);

  // ChebConv into d_out: k=0 dense (+bias), k=1..4 fused gather+recurrence+GEMM
  k_gemm32b<<<cdiv(N, 8), B, 0, stream>>>(patch, cheb_w, cheb_b, out, N);
  k_cheb4<<<cdiv(N, 32), B, 0, stream>>>((const float4*)patch, nullptr, grptr, eg,
                                         cheb_w + 1024, perm, 1.f,
                                         (float4*)R0, (float4*)out, N);
  k_cheb4<<<cdiv(N, 32), B, 0, stream>>>((const float4*)R0, (const float4*)patch,
                                         grptr, eg, cheb_w + 2048, perm, 2.f,
                                         (float4*)R1, (float4*)out, N);
  k_cheb4<<<cdiv(N, 32), B, 0, stream>>>((const float4*)R1, (const float4*)R0,
                                         grptr, eg, cheb_w + 3072, perm, 2.f,
                                         (float4*)R0, (float4*)out, N);
  k_cheb4<<<cdiv(N, 32), B, 0, stream>>>((const float4*)R0, (const float4*)R1,
                                         grptr, eg, cheb_w + 4096, perm, 2.f,
                                         nullptr, (float4*)out, N);

  // SuperGAT: h (fp16 head-packed) = x @ lin_w, then fused no-max-softmax
  // gather (1 random request/edge; bl/br recomputed in-register) + epilogue
  k_gemmh<<<cdiv(N, 4), B, 0, stream>>>(out, lin_w, h, N);
  k_expgat4<<<cdiv(N, 16), B, 0, stream>>>((const int2*)h, grptr, eg, att_l, att_r,
                                           gat_b, perm, out, bns, N);
  k_bnfinal<<<cdiv(NC, B), B, 0, stream>>>(out, bns, bn_g, bn_b, out, N);
}